// Round 10
// baseline (308.682 us; speedup 1.0000x reference)
//
#include <hip/hip_runtime.h>
#include <math.h>

#define NH 4
#define NEG_SLOPE 0.2f
#define BKT_SHIFT 8            // 256 nodes per bucket
#define EPB 4096               // edges per binscatter block

typedef __attribute__((ext_vector_type(8))) short bf16x8;
typedef __attribute__((ext_vector_type(4))) float f32x4;

__device__ __forceinline__ float blo(unsigned u) { return __uint_as_float(u << 16); }
__device__ __forceinline__ float bhi(unsigned u) { return __uint_as_float(u & 0xFFFF0000u); }
__device__ __forceinline__ unsigned short rne(float f) {
    unsigned u = __float_as_uint(f);
    u += 0x7FFFu + ((u >> 16) & 1u);
    return (unsigned short)(u >> 16);
}
__device__ __forceinline__ unsigned pack2(float a, float b) {
    return (unsigned)rne(a) | ((unsigned)rne(b) << 16);
}

// ---------- fused prep: degree count (x4 ILP) + h->bf16 cast + W cast ----------
__global__ __launch_bounds__(256) void k_prep(
    const int* __restrict__ dst, int* __restrict__ deg_i, int E,
    const float* __restrict__ h, unsigned* __restrict__ hbu, int n_pairs,
    const float* __restrict__ Wfc, const float* __restrict__ Wres,
    unsigned* __restrict__ wcat) {
    int t = blockIdx.x * blockDim.x + threadIdx.x;
    int base = t * 4;
    if (base + 3 < E) {
        int4 d = ((const int4*)dst)[t];
        atomicAdd(deg_i + d.x, 1);
        atomicAdd(deg_i + d.y, 1);
        atomicAdd(deg_i + d.z, 1);
        atomicAdd(deg_i + d.w, 1);
    } else if (base < E) {
        for (int e = base; e < E; e++) atomicAdd(deg_i + dst[e], 1);
    }
    if (t < n_pairs) {
        float2 v = ((const float2*)h)[t];
        hbu[t] = pack2(v.x, v.y);
    }
    if (t < 32768) {
        int col = t >> 7, kk = t & 127;
        const float* srcp = (col < 128) ? (Wfc + (size_t)col * 256)
                                        : (Wres + (size_t)(col - 128) * 256);
        float2 v = ((const float2*)srcp)[kk];
        wcat[t] = pack2(v.x, v.y);
    }
}

// ---------- cos table: tab[q][64 pairs] = cos(((q+.5)/32768)*w + b), bf16 pairs ----------
__global__ __launch_bounds__(256) void k_costab(
    const float* __restrict__ w_t, const float* __restrict__ b_t,
    unsigned* __restrict__ tab) {
    int t = blockIdx.x * blockDim.x + threadIdx.x;   // total = 32768*64
    int q = t >> 6, p = t & 63;
    float tv = ((float)q + 0.5f) * (1.0f / 32768.0f);
    float2 wv = ((const float2*)w_t)[p];
    float2 bv = ((const float2*)b_t)[p];
    tab[t] = pack2(__cosf(fmaf(tv, wv.x, bv.x)), __cosf(fmaf(tv, wv.y, bv.y)));
}

// ---------- scan (2-stage; k_scandown folds partial-scan; also inits bucket cursors) ----
__global__ __launch_bounds__(1024) void k_blocksum(const int* __restrict__ deg_i,
                                                   int* __restrict__ partials, int N) {
    __shared__ int wsum[16];
    int tid = threadIdx.x, lane = tid & 63, wid = tid >> 6;
    int i = blockIdx.x * 1024 + tid;
    int v = (i < N) ? deg_i[i] : 0;
#pragma unroll
    for (int off = 32; off > 0; off >>= 1) v += __shfl_xor(v, off, 64);
    if (lane == 0) wsum[wid] = v;
    __syncthreads();
    if (tid == 0) {
        int s = 0;
#pragma unroll
        for (int k = 0; k < 16; k++) s += wsum[k];
        partials[blockIdx.x] = s;
    }
}

__global__ __launch_bounds__(1024) void k_scandown(const int* __restrict__ deg_i,
                                                   const int* __restrict__ partials,
                                                   int* __restrict__ row_start,
                                                   int* __restrict__ bkt_cursor,
                                                   int N, int B) {
    __shared__ int wsum[16];
    __shared__ int s_off;
    int tid = threadIdx.x, lane = tid & 63, wid = tid >> 6;
    if (wid == 0) {
        int pv = (lane < B) ? partials[lane] : 0;
        int px = pv;
#pragma unroll
        for (int off = 1; off < 64; off <<= 1) {
            int y = __shfl_up(px, off, 64);
            if (lane >= off) px += y;
        }
        if (lane == (int)blockIdx.x) s_off = px - pv;
        if (blockIdx.x == 0 && lane == B - 1) row_start[N] = px;
    }
    int i = blockIdx.x * 1024 + tid;
    int v = (i < N) ? deg_i[i] : 0;
    int x = v;
#pragma unroll
    for (int off = 1; off < 64; off <<= 1) {
        int y = __shfl_up(x, off, 64);
        if (lane >= off) x += y;
    }
    if (lane == 63) wsum[wid] = x;
    __syncthreads();
    if (wid == 0 && lane < 16) {
        int s = wsum[lane];
#pragma unroll
        for (int off = 1; off < 16; off <<= 1) {
            int y = __shfl_up(s, off, 64);
            if (lane >= off) s += y;
        }
        wsum[lane] = s;
    }
    __syncthreads();
    if (i < N) {
        int base = s_off + (wid > 0 ? wsum[wid - 1] : 0);
        int excl = base + x - v;
        row_start[i] = excl;
        if ((i & 255) == 0) bkt_cursor[i >> BKT_SHIFT] = excl;
    }
}

// ---------- pass 1: bin edges into 256-node buckets (LDS count + chunk reservation) ----
__global__ __launch_bounds__(256) void k_binscatter(
    const int* __restrict__ src, const int* __restrict__ dst,
    const float* __restrict__ tt, int* __restrict__ bkt_cursor,
    uint2* __restrict__ staged, int E, int NB) {
    __shared__ int cnt[1024];
    __shared__ int basep[1024];
    int e0 = blockIdx.x * EPB;
    int tid = threadIdx.x;
    for (int b = tid; b < NB; b += 256) cnt[b] = 0;
    __syncthreads();
#pragma unroll
    for (int k = 0; k < EPB / 256; k++) {
        int e = e0 + k * 256 + tid;
        if (e < E) atomicAdd(&cnt[dst[e] >> BKT_SHIFT], 1);
    }
    __syncthreads();
    for (int b = tid; b < NB; b += 256) {
        int c = cnt[b];
        basep[b] = (c > 0) ? atomicAdd(bkt_cursor + b, c) : 0;
        cnt[b] = 0;          // reuse as rank counter
    }
    __syncthreads();
#pragma unroll
    for (int k = 0; k < EPB / 256; k++) {
        int e = e0 + k * 256 + tid;
        if (e < E) {
            int d = dst[e];
            int b = d >> BKT_SHIFT;
            int r = atomicAdd(&cnt[b], 1);
            unsigned tq = min((unsigned)(tt[e] * 32768.0f), 32767u);
            staged[basep[b] + r] =
                make_uint2(((unsigned)src[e] << 15) | tq, (unsigned)(d & 255));
        }
    }
}

// ---------- pass 2: one block per bucket; LDS node cursors; local est scatter ----------
__global__ __launch_bounds__(256) void k_binsort(
    const uint2* __restrict__ staged, const int* __restrict__ row_start,
    unsigned* __restrict__ est, int N) {
    __shared__ int cur[256];
    int b = blockIdx.x;
    int n0 = b << BKT_SHIFT;
    int n1 = min(n0 + 256, N);
    int tid = threadIdx.x;
    if (tid < n1 - n0) cur[tid] = row_start[n0 + tid];
    __syncthreads();
    int s0 = row_start[n0], s1 = row_start[n1];
    for (int p = s0 + tid; p < s1; p += 256) {
        uint2 v = staged[p];
        int pos = atomicAdd(&cur[v.y], 1);
        est[pos] = v.x;
    }
}

// ---------- per-edge helpers ----------
__device__ __forceinline__ void agg_edge(unsigned u, float wgt,
                                         const uint4* __restrict__ h4,
                                         const uint4* __restrict__ t4,
                                         int i, float* aH, float* aT) {
    int s = (int)(u >> 15);
    int q = (int)(u & 0x7FFFu);
    uint4 hv = h4[(size_t)s * 16 + i];
    uint4 tv = t4[(size_t)q * 16 + i];
    aH[0] += wgt * blo(hv.x); aH[1] += wgt * bhi(hv.x);
    aH[2] += wgt * blo(hv.y); aH[3] += wgt * bhi(hv.y);
    aH[4] += wgt * blo(hv.z); aH[5] += wgt * bhi(hv.z);
    aH[6] += wgt * blo(hv.w); aH[7] += wgt * bhi(hv.w);
    aT[0] += wgt * blo(tv.x); aT[1] += wgt * bhi(tv.x);
    aT[2] += wgt * blo(tv.y); aT[3] += wgt * bhi(tv.y);
    aT[4] += wgt * blo(tv.z); aT[5] += wgt * bhi(tv.z);
    aT[6] += wgt * blo(tv.w); aT[7] += wgt * bhi(tv.w);
}

__device__ __forceinline__ void attn_edge(unsigned u, bool valid, const uint4* __restrict__ f4,
                                          int i, int hd, const float* __restrict__ el,
                                          float erh, float* acc, float& den) {
    int s = (int)(u >> 15);
    float elh = el[(size_t)s * 4 + hd];
    uint4 fv = f4[(size_t)s * 16 + i];
    float w = elh + erh; w = w > 0.f ? w : NEG_SLOPE * w;
    float ex = valid ? __expf(w) : 0.f;
    acc[0] = fmaf(ex, blo(fv.x), acc[0]); acc[1] = fmaf(ex, bhi(fv.x), acc[1]);
    acc[2] = fmaf(ex, blo(fv.y), acc[2]); acc[3] = fmaf(ex, bhi(fv.y), acc[3]);
    acc[4] = fmaf(ex, blo(fv.z), acc[4]); acc[5] = fmaf(ex, bhi(fv.z), acc[5]);
    acc[6] = fmaf(ex, blo(fv.w), acc[6]); acc[7] = fmaf(ex, bhi(fv.w), acc[7]);
    den += ex;
}

// ---------- mailbox mean: wave/node, 16 lanes/edge, 4 groups, unroll-4, cos table ------
__global__ __launch_bounds__(256) void k_agg(
    const unsigned* __restrict__ hbu, const unsigned* __restrict__ costab,
    const unsigned* __restrict__ est, const int* __restrict__ row_start,
    unsigned* __restrict__ htu, int N) {
    int n = blockIdx.x * 4 + (threadIdx.x >> 6);
    if (n >= N) return;
    int lane = threadIdx.x & 63;
    int g = lane >> 4, i = lane & 15;
    int rs = row_start[n], re = row_start[n + 1];
    const uint4* h4 = (const uint4*)hbu;
    const uint4* t4 = (const uint4*)costab;
    float aH[8] = {}, aT[8] = {};
    for (int e = rs + g; e < re; e += 16) {
        int e1 = e + 4, e2 = e + 8, e3 = e + 12;
        bool v1 = e1 < re, v2 = e2 < re, v3 = e3 < re;
        unsigned u0 = est[e];
        unsigned u1 = est[v1 ? e1 : e];
        unsigned u2 = est[v2 ? e2 : e];
        unsigned u3 = est[v3 ? e3 : e];
        agg_edge(u0, 1.0f, h4, t4, i, aH, aT);
        agg_edge(u1, v1 ? 1.0f : 0.0f, h4, t4, i, aH, aT);
        agg_edge(u2, v2 ? 1.0f : 0.0f, h4, t4, i, aH, aT);
        agg_edge(u3, v3 ? 1.0f : 0.0f, h4, t4, i, aH, aT);
    }
#pragma unroll
    for (int off = 16; off <= 32; off <<= 1) {
#pragma unroll
        for (int k = 0; k < 8; k++) {
            aH[k] += __shfl_xor(aH[k], off, 64);
            aT[k] += __shfl_xor(aT[k], off, 64);
        }
    }
    if (g == 0) {
        int deg = re - rs;
        float idg = (deg > 0) ? 1.0f / (float)deg : 1.0f;
        uint4* ht4 = (uint4*)htu;
        uint4 oh, ot;
        oh.x = pack2(aH[0] * idg, aH[1] * idg);
        oh.y = pack2(aH[2] * idg, aH[3] * idg);
        oh.z = pack2(aH[4] * idg, aH[5] * idg);
        oh.w = pack2(aH[6] * idg, aH[7] * idg);
        ot.x = pack2(aT[0] * idg, aT[1] * idg);
        ot.y = pack2(aT[2] * idg, aT[3] * idg);
        ot.z = pack2(aT[4] * idg, aT[5] * idg);
        ot.w = pack2(aT[6] * idg, aT[7] * idg);
        ht4[(size_t)n * 32 + i]      = oh;
        ht4[(size_t)n * 32 + 16 + i] = ot;
    }
}

// ---------- MFMA GEMM: LDS-staged A tile (64 rows), 4 waves x 64-col strips ----------
__global__ __launch_bounds__(256) void k_gemm(
    const unsigned short* __restrict__ ht, const unsigned short* __restrict__ wcat,
    unsigned short* __restrict__ feat, float* __restrict__ res_out, int N) {
    __shared__ __align__(16) unsigned short As[64 * 264];
    int tid = threadIdx.x;
    int row0 = blockIdx.x * 64;
    const uint4* src4 = (const uint4*)ht;
    for (int idx = tid; idx < 64 * 32; idx += 256) {
        int rl = idx >> 5, c16 = idx & 31;
        int gr = row0 + rl; if (gr >= N) gr = N - 1;
        uint4 v = src4[(size_t)gr * 32 + c16];
        *(uint4*)(As + rl * 264 + c16 * 8) = v;
    }
    __syncthreads();
    int wave = tid >> 6, lane = tid & 63;
    int r = lane & 15, q = lane >> 4;
    int colbase = wave * 64;
    const bf16x8* bbase = (const bf16x8*)wcat + (size_t)(colbase + r) * 32;
    const unsigned short* abase = As + r * 264 + q * 8;
    f32x4 acc[4][4] = {};
#pragma unroll
    for (int ks = 0; ks < 8; ks++) {
        bf16x8 a[4], b[4];
#pragma unroll
        for (int rt = 0; rt < 4; rt++)
            a[rt] = *(const bf16x8*)(abase + rt * (16 * 264) + ks * 32);
#pragma unroll
        for (int ct = 0; ct < 4; ct++)
            b[ct] = bbase[(size_t)ct * (16 * 32) + ks * 4 + q];
#pragma unroll
        for (int rt = 0; rt < 4; rt++)
#pragma unroll
            for (int ct = 0; ct < 4; ct++)
                acc[rt][ct] = __builtin_amdgcn_mfma_f32_16x16x32_bf16(a[rt], b[ct], acc[rt][ct], 0, 0, 0);
    }
#pragma unroll
    for (int rt = 0; rt < 4; rt++) {
        int rb = row0 + rt * 16 + q * 4;
#pragma unroll
        for (int ct = 0; ct < 4; ct++) {
            int col = colbase + ct * 16 + r;
#pragma unroll
            for (int reg = 0; reg < 4; reg++) {
                int row = rb + reg;
                if (row >= N) continue;
                float v = acc[rt][ct][reg];
                if (col < 128) feat[(size_t)row * 128 + col] = rne(v);
                else           res_out[(size_t)row * 128 + (col - 128)] = v;
            }
        }
    }
}

// ---------- el/er ----------
__global__ void k_el_er(const unsigned* __restrict__ featu,
                        const float* __restrict__ attn_l, const float* __restrict__ attn_r,
                        float* __restrict__ el, float* __restrict__ er, int NH4) {
    int t = blockIdx.x * blockDim.x + threadIdx.x;
    if (t >= NH4) return;
    int n = t >> 2, hd = t & 3;
    const unsigned* f = featu + (size_t)n * 64 + hd * 16;
    const float2* al = (const float2*)(attn_l + hd * 32);
    const float2* ar = (const float2*)(attn_r + hd * 32);
    float sl = 0.f, sr = 0.f;
#pragma unroll
    for (int i = 0; i < 16; i++) {
        unsigned u = f[i];
        float f0 = blo(u), f1 = bhi(u);
        float2 a = al[i], b = ar[i];
        sl = fmaf(f0, a.x, fmaf(f1, a.y, sl));
        sr = fmaf(f0, b.x, fmaf(f1, b.y, sr));
    }
    el[t] = sl;
    er[t] = sr;
}

// ---------- fused attention: wave/node, 16 lanes/edge, 4 groups, unroll-4 ----------
__global__ __launch_bounds__(256) void k_attn(
    const unsigned* __restrict__ est, const int* __restrict__ row_start,
    const float* __restrict__ el, const float* __restrict__ er,
    const unsigned* __restrict__ featu, const float* __restrict__ bias,
    float* __restrict__ out, int N) {
    int n = blockIdx.x * 4 + (threadIdx.x >> 6);
    if (n >= N) return;
    int lane = threadIdx.x & 63;
    int g = lane >> 4, i = lane & 15;
    int hd = i >> 2;
    int rs = row_start[n], re = row_start[n + 1];
    float erh = er[(size_t)n * 4 + hd];
    const uint4* f4 = (const uint4*)featu;
    float acc[8] = {};
    float den = 0.f;
    for (int e = rs + g; e < re; e += 16) {
        int e1 = e + 4, e2 = e + 8, e3 = e + 12;
        bool v1 = e1 < re, v2 = e2 < re, v3 = e3 < re;
        unsigned u0 = est[e];
        unsigned u1 = est[v1 ? e1 : e];
        unsigned u2 = est[v2 ? e2 : e];
        unsigned u3 = est[v3 ? e3 : e];
        attn_edge(u0, true, f4, i, hd, el, erh, acc, den);
        attn_edge(u1, v1, f4, i, hd, el, erh, acc, den);
        attn_edge(u2, v2, f4, i, hd, el, erh, acc, den);
        attn_edge(u3, v3, f4, i, hd, el, erh, acc, den);
    }
#pragma unroll
    for (int off = 16; off <= 32; off <<= 1) {
#pragma unroll
        for (int k = 0; k < 8; k++) acc[k] += __shfl_xor(acc[k], off, 64);
        den += __shfl_xor(den, off, 64);
    }
    if (g == 0) {
        float id = 1.0f / fmaxf(den, 1e-9f);
        float* op = out + (size_t)n * 128 + i * 8;
        const float* bp = bias + i * 8;
        float4 o0 = ((const float4*)op)[0], o1 = ((const float4*)op)[1];
        float4 b0 = ((const float4*)bp)[0], b1 = ((const float4*)bp)[1];
        float4 r0, r1;
        r0.x = fmaf(acc[0], id, o0.x + b0.x);
        r0.y = fmaf(acc[1], id, o0.y + b0.y);
        r0.z = fmaf(acc[2], id, o0.z + b0.z);
        r0.w = fmaf(acc[3], id, o0.w + b0.w);
        r1.x = fmaf(acc[4], id, o1.x + b1.x);
        r1.y = fmaf(acc[5], id, o1.y + b1.y);
        r1.z = fmaf(acc[6], id, o1.z + b1.z);
        r1.w = fmaf(acc[7], id, o1.w + b1.w);
        r0.x = r0.x > 0.f ? r0.x : (__expf(r0.x) - 1.0f);
        r0.y = r0.y > 0.f ? r0.y : (__expf(r0.y) - 1.0f);
        r0.z = r0.z > 0.f ? r0.z : (__expf(r0.z) - 1.0f);
        r0.w = r0.w > 0.f ? r0.w : (__expf(r0.w) - 1.0f);
        r1.x = r1.x > 0.f ? r1.x : (__expf(r1.x) - 1.0f);
        r1.y = r1.y > 0.f ? r1.y : (__expf(r1.y) - 1.0f);
        r1.z = r1.z > 0.f ? r1.z : (__expf(r1.z) - 1.0f);
        r1.w = r1.w > 0.f ? r1.w : (__expf(r1.w) - 1.0f);
        ((float4*)op)[0] = r0;
        ((float4*)op)[1] = r1;
    }
}

extern "C" void kernel_launch(void* const* d_in, const int* in_sizes, int n_in,
                              void* d_out, int out_size, void* d_ws, size_t ws_size,
                              hipStream_t stream) {
    const float* h     = (const float*)d_in[0];
    const float* tt    = (const float*)d_in[1];
    const int*   src   = (const int*)d_in[2];
    const int*   dst   = (const int*)d_in[3];
    const float* w_t   = (const float*)d_in[5];
    const float* b_t   = (const float*)d_in[6];
    const float* W_fc  = (const float*)d_in[7];
    const float* al    = (const float*)d_in[8];
    const float* ar    = (const float*)d_in[9];
    const float* W_res = (const float*)d_in[10];
    const float* bias  = (const float*)d_in[11];

    int N = in_sizes[0] / 128;
    int E = in_sizes[1];
    int B = (N + 1023) / 1024;           // k_scandown assumes B<=64
    int NB = (N + 255) >> BKT_SHIFT;     // buckets; LDS arrays assume NB<=1024

    char* ws = (char*)d_ws;
    size_t off = 0;
    auto alloc = [&](size_t bytes) { void* p = ws + off; off = (off + bytes + 15) & ~(size_t)15; return p; };
    unsigned* htu     = (unsigned*)alloc((size_t)N * 128 * 4);
    unsigned* hbu     = (unsigned*)alloc((size_t)N * 64 * 4);
    unsigned* featu   = (unsigned*)alloc((size_t)N * 64 * 4);   // also aliased as staged
    unsigned* wcat    = (unsigned*)alloc(32768 * 4);
    unsigned* costab  = (unsigned*)alloc((size_t)32768 * 64 * 4);
    float*    el      = (float*)alloc((size_t)N * NH * 4);
    float*    er      = (float*)alloc((size_t)N * NH * 4);
    int*      deg_i   = (int*)alloc((size_t)N * 4);
    int*      row_st  = (int*)alloc((size_t)(N + 1) * 4);
    int*      bkt_cur = (int*)alloc((size_t)NB * 4);
    int*      parts   = (int*)alloc((size_t)B * 4);
    unsigned* est     = (unsigned*)alloc((size_t)E * 4);
    uint2*    staged  = (uint2*)featu;   // consumed by k_binsort before k_gemm writes featu

    hipMemsetAsync(deg_i, 0, (size_t)N * 4, stream);

    int prep_n = N * 64;
    hipLaunchKernelGGL(k_prep, dim3((prep_n + 255) / 256), dim3(256), 0, stream,
                       dst, deg_i, E, h, hbu, prep_n, W_fc, W_res, wcat);
    hipLaunchKernelGGL(k_costab, dim3((32768 * 64) / 256), dim3(256), 0, stream,
                       w_t, b_t, costab);
    hipLaunchKernelGGL(k_blocksum, dim3(B), dim3(1024), 0, stream, deg_i, parts, N);
    hipLaunchKernelGGL(k_scandown, dim3(B), dim3(1024), 0, stream,
                       deg_i, parts, row_st, bkt_cur, N, B);
    hipLaunchKernelGGL(k_binscatter, dim3((E + EPB - 1) / EPB), dim3(256), 0, stream,
                       src, dst, tt, bkt_cur, staged, E, NB);
    hipLaunchKernelGGL(k_binsort, dim3(NB), dim3(256), 0, stream,
                       staged, row_st, est, N);
    hipLaunchKernelGGL(k_agg, dim3((N + 3) / 4), dim3(256), 0, stream,
                       hbu, costab, est, row_st, htu, N);
    hipLaunchKernelGGL(k_gemm, dim3((N + 63) / 64), dim3(256), 0, stream,
                       (const unsigned short*)htu, (const unsigned short*)wcat,
                       (unsigned short*)featu, (float*)d_out, N);
    hipLaunchKernelGGL(k_el_er, dim3((N * NH + 255) / 256), dim3(256), 0, stream,
                       featu, al, ar, el, er, N * NH);
    hipLaunchKernelGGL(k_attn, dim3((N + 3) / 4), dim3(256), 0, stream,
                       est, row_st, el, er, featu, bias, (float*)d_out, N);
}

// Round 11
// 283.639 us; speedup vs baseline: 1.0883x; 1.0883x over previous
//
#include <hip/hip_runtime.h>
#include <math.h>

#define NH 4
#define NEG_SLOPE 0.2f
#define BKT_SHIFT 8            // 256 nodes per bucket
#define EPB 4096               // edges per binscatter block
#define INV2PI 0.15915494309189535f
#define LOG2E  1.4426950408889634f

typedef __attribute__((ext_vector_type(8))) short bf16x8;
typedef __attribute__((ext_vector_type(4))) float f32x4;

__device__ __forceinline__ float blo(unsigned u) { return __uint_as_float(u << 16); }
__device__ __forceinline__ float bhi(unsigned u) { return __uint_as_float(u & 0xFFFF0000u); }
__device__ __forceinline__ unsigned short rne(float f) {
    unsigned u = __float_as_uint(f);
    u += 0x7FFFu + ((u >> 16) & 1u);
    return (unsigned short)(u >> 16);
}
__device__ __forceinline__ unsigned pack2(float a, float b) {
    return (unsigned)rne(a) | ((unsigned)rne(b) << 16);
}

// ---------- fused prep: degree count (x4 ILP) + h->bf16 cast + W cast + w/b prescale ----
__global__ __launch_bounds__(256) void k_prep(
    const int* __restrict__ dst, int* __restrict__ deg_i, int E,
    const float* __restrict__ h, unsigned* __restrict__ hbu, int n_pairs,
    const float* __restrict__ Wfc, const float* __restrict__ Wres,
    unsigned* __restrict__ wcat,
    const float* __restrict__ w_t, const float* __restrict__ b_t,
    float2* __restrict__ w_s, float2* __restrict__ b_s) {
    int t = blockIdx.x * blockDim.x + threadIdx.x;
    int base = t * 4;
    if (base + 3 < E) {
        int4 d = ((const int4*)dst)[t];
        atomicAdd(deg_i + d.x, 1);
        atomicAdd(deg_i + d.y, 1);
        atomicAdd(deg_i + d.z, 1);
        atomicAdd(deg_i + d.w, 1);
    } else if (base < E) {
        for (int e = base; e < E; e++) atomicAdd(deg_i + dst[e], 1);
    }
    if (t < n_pairs) {
        float2 v = ((const float2*)h)[t];
        hbu[t] = pack2(v.x, v.y);
    }
    if (t < 32768) {
        int col = t >> 7, kk = t & 127;
        const float* srcp = (col < 128) ? (Wfc + (size_t)col * 256)
                                        : (Wres + (size_t)(col - 128) * 256);
        float2 v = ((const float2*)srcp)[kk];
        wcat[t] = pack2(v.x, v.y);
    }
    if (t < 64) {   // prescale time-encoder params to revolutions for raw v_cos
        float2 wv = ((const float2*)w_t)[t];
        float2 bv = ((const float2*)b_t)[t];
        w_s[t] = make_float2(wv.x * INV2PI, wv.y * INV2PI);
        b_s[t] = make_float2(bv.x * INV2PI, bv.y * INV2PI);
    }
}

// ---------- scan (2-stage; k_scandown folds partial-scan; also inits bucket cursors) ----
__global__ __launch_bounds__(1024) void k_blocksum(const int* __restrict__ deg_i,
                                                   int* __restrict__ partials, int N) {
    __shared__ int wsum[16];
    int tid = threadIdx.x, lane = tid & 63, wid = tid >> 6;
    int i = blockIdx.x * 1024 + tid;
    int v = (i < N) ? deg_i[i] : 0;
#pragma unroll
    for (int off = 32; off > 0; off >>= 1) v += __shfl_xor(v, off, 64);
    if (lane == 0) wsum[wid] = v;
    __syncthreads();
    if (tid == 0) {
        int s = 0;
#pragma unroll
        for (int k = 0; k < 16; k++) s += wsum[k];
        partials[blockIdx.x] = s;
    }
}

__global__ __launch_bounds__(1024) void k_scandown(const int* __restrict__ deg_i,
                                                   const int* __restrict__ partials,
                                                   int* __restrict__ row_start,
                                                   int* __restrict__ bkt_cursor,
                                                   int N, int B) {
    __shared__ int wsum[16];
    __shared__ int s_off;
    int tid = threadIdx.x, lane = tid & 63, wid = tid >> 6;
    if (wid == 0) {
        int pv = (lane < B) ? partials[lane] : 0;
        int px = pv;
#pragma unroll
        for (int off = 1; off < 64; off <<= 1) {
            int y = __shfl_up(px, off, 64);
            if (lane >= off) px += y;
        }
        if (lane == (int)blockIdx.x) s_off = px - pv;
        if (blockIdx.x == 0 && lane == B - 1) row_start[N] = px;
    }
    int i = blockIdx.x * 1024 + tid;
    int v = (i < N) ? deg_i[i] : 0;
    int x = v;
#pragma unroll
    for (int off = 1; off < 64; off <<= 1) {
        int y = __shfl_up(x, off, 64);
        if (lane >= off) x += y;
    }
    if (lane == 63) wsum[wid] = x;
    __syncthreads();
    if (wid == 0 && lane < 16) {
        int s = wsum[lane];
#pragma unroll
        for (int off = 1; off < 16; off <<= 1) {
            int y = __shfl_up(s, off, 64);
            if (lane >= off) s += y;
        }
        wsum[lane] = s;
    }
    __syncthreads();
    if (i < N) {
        int base = s_off + (wid > 0 ? wsum[wid - 1] : 0);
        int excl = base + x - v;
        row_start[i] = excl;
        if ((i & 255) == 0) bkt_cursor[i >> BKT_SHIFT] = excl;
    }
}

// ---------- pass 1: bin edges into 256-node buckets (LDS count + chunk reservation) ----
__global__ __launch_bounds__(256) void k_binscatter(
    const int* __restrict__ src, const int* __restrict__ dst,
    const float* __restrict__ tt, int* __restrict__ bkt_cursor,
    uint2* __restrict__ staged, int E, int NB) {
    __shared__ int cnt[1024];
    __shared__ int basep[1024];
    int e0 = blockIdx.x * EPB;
    int tid = threadIdx.x;
    for (int b = tid; b < NB; b += 256) cnt[b] = 0;
    __syncthreads();
#pragma unroll
    for (int k = 0; k < EPB / 256; k++) {
        int e = e0 + k * 256 + tid;
        if (e < E) atomicAdd(&cnt[dst[e] >> BKT_SHIFT], 1);
    }
    __syncthreads();
    for (int b = tid; b < NB; b += 256) {
        int c = cnt[b];
        basep[b] = (c > 0) ? atomicAdd(bkt_cursor + b, c) : 0;
        cnt[b] = 0;          // reuse as rank counter
    }
    __syncthreads();
#pragma unroll
    for (int k = 0; k < EPB / 256; k++) {
        int e = e0 + k * 256 + tid;
        if (e < E) {
            int d = dst[e];
            int b = d >> BKT_SHIFT;
            int r = atomicAdd(&cnt[b], 1);
            unsigned tq = min((unsigned)(tt[e] * 32768.0f), 32767u);
            staged[basep[b] + r] =
                make_uint2(((unsigned)src[e] << 15) | tq, (unsigned)(d & 255));
        }
    }
}

// ---------- pass 2: one block per bucket; LDS node cursors; local est scatter ----------
__global__ __launch_bounds__(256) void k_binsort(
    const uint2* __restrict__ staged, const int* __restrict__ row_start,
    unsigned* __restrict__ est, int N) {
    __shared__ int cur[256];
    int b = blockIdx.x;
    int n0 = b << BKT_SHIFT;
    int n1 = min(n0 + 256, N);
    int tid = threadIdx.x;
    if (tid < n1 - n0) cur[tid] = row_start[n0 + tid];
    __syncthreads();
    int s0 = row_start[n0], s1 = row_start[n1];
    for (int p = s0 + tid; p < s1; p += 256) {
        uint2 v = staged[p];
        int pos = atomicAdd(&cur[v.y], 1);
        est[pos] = v.x;
    }
}

// ---------- per-edge helpers ----------
__device__ __forceinline__ void agg_edge(unsigned u, float wgt, const uint4* __restrict__ h4,
                                         int i, float4 wa, float4 wb, float4 ba, float4 bb,
                                         float* aH, float* aT) {
    int s = (int)(u >> 15);
    float t = (float)((u & 0x7FFFu)) * (1.0f / 32768.0f) + (0.5f / 32768.0f);
    uint4 hv = h4[(size_t)s * 16 + i];
    aH[0] += wgt * blo(hv.x); aH[1] += wgt * bhi(hv.x);
    aH[2] += wgt * blo(hv.y); aH[3] += wgt * bhi(hv.y);
    aH[4] += wgt * blo(hv.z); aH[5] += wgt * bhi(hv.z);
    aH[6] += wgt * blo(hv.w); aH[7] += wgt * bhi(hv.w);
    // w/b are prescaled to revolutions: cos(2π·(t·w'+b')) == cos(t·w+b)
    aT[0] += wgt * __builtin_amdgcn_cosf(fmaf(t, wa.x, ba.x));
    aT[1] += wgt * __builtin_amdgcn_cosf(fmaf(t, wa.y, ba.y));
    aT[2] += wgt * __builtin_amdgcn_cosf(fmaf(t, wa.z, ba.z));
    aT[3] += wgt * __builtin_amdgcn_cosf(fmaf(t, wa.w, ba.w));
    aT[4] += wgt * __builtin_amdgcn_cosf(fmaf(t, wb.x, bb.x));
    aT[5] += wgt * __builtin_amdgcn_cosf(fmaf(t, wb.y, bb.y));
    aT[6] += wgt * __builtin_amdgcn_cosf(fmaf(t, wb.z, bb.z));
    aT[7] += wgt * __builtin_amdgcn_cosf(fmaf(t, wb.w, bb.w));
}

__device__ __forceinline__ void attn_edge(unsigned u, bool valid, const uint4* __restrict__ f4,
                                          int i, int hd, const float* __restrict__ el,
                                          float erh, float* acc, float& den) {
    int s = (int)(u >> 15);
    float elh = el[(size_t)s * 4 + hd];          // el,er prescaled by log2(e)
    uint4 fv = f4[(size_t)s * 16 + i];
    float w = elh + erh; w = w > 0.f ? w : NEG_SLOPE * w;   // leaky commutes with +scale
    float ex = valid ? __builtin_amdgcn_exp2f(w) : 0.f;
    acc[0] = fmaf(ex, blo(fv.x), acc[0]); acc[1] = fmaf(ex, bhi(fv.x), acc[1]);
    acc[2] = fmaf(ex, blo(fv.y), acc[2]); acc[3] = fmaf(ex, bhi(fv.y), acc[3]);
    acc[4] = fmaf(ex, blo(fv.z), acc[4]); acc[5] = fmaf(ex, bhi(fv.z), acc[5]);
    acc[6] = fmaf(ex, blo(fv.w), acc[6]); acc[7] = fmaf(ex, bhi(fv.w), acc[7]);
    den += ex;
}

// ---------- mailbox mean: wave/node, 16 lanes/edge, 4 groups, unroll-4 ----------
__global__ __launch_bounds__(256) void k_agg(
    const unsigned* __restrict__ hbu, const unsigned* __restrict__ est,
    const int* __restrict__ row_start,
    const float2* __restrict__ w_s, const float2* __restrict__ b_s,
    unsigned* __restrict__ htu, int N) {
    int n = blockIdx.x * 4 + (threadIdx.x >> 6);
    if (n >= N) return;
    int lane = threadIdx.x & 63;
    int g = lane >> 4, i = lane & 15;
    int rs = row_start[n], re = row_start[n + 1];
    const uint4* h4 = (const uint4*)hbu;
    float4 wa = ((const float4*)w_s)[2 * i], wb = ((const float4*)w_s)[2 * i + 1];
    float4 ba = ((const float4*)b_s)[2 * i], bb = ((const float4*)b_s)[2 * i + 1];
    float aH[8] = {}, aT[8] = {};
    for (int e = rs + g; e < re; e += 16) {
        int e1 = e + 4, e2 = e + 8, e3 = e + 12;
        bool v1 = e1 < re, v2 = e2 < re, v3 = e3 < re;
        unsigned u0 = est[e];
        unsigned u1 = est[v1 ? e1 : e];
        unsigned u2 = est[v2 ? e2 : e];
        unsigned u3 = est[v3 ? e3 : e];
        agg_edge(u0, 1.0f, h4, i, wa, wb, ba, bb, aH, aT);
        agg_edge(u1, v1 ? 1.0f : 0.0f, h4, i, wa, wb, ba, bb, aH, aT);
        agg_edge(u2, v2 ? 1.0f : 0.0f, h4, i, wa, wb, ba, bb, aH, aT);
        agg_edge(u3, v3 ? 1.0f : 0.0f, h4, i, wa, wb, ba, bb, aH, aT);
    }
#pragma unroll
    for (int off = 16; off <= 32; off <<= 1) {
#pragma unroll
        for (int k = 0; k < 8; k++) {
            aH[k] += __shfl_xor(aH[k], off, 64);
            aT[k] += __shfl_xor(aT[k], off, 64);
        }
    }
    if (g == 0) {
        int deg = re - rs;
        float idg = (deg > 0) ? 1.0f / (float)deg : 1.0f;
        uint4* ht4 = (uint4*)htu;
        uint4 oh, ot;
        oh.x = pack2(aH[0] * idg, aH[1] * idg);
        oh.y = pack2(aH[2] * idg, aH[3] * idg);
        oh.z = pack2(aH[4] * idg, aH[5] * idg);
        oh.w = pack2(aH[6] * idg, aH[7] * idg);
        ot.x = pack2(aT[0] * idg, aT[1] * idg);
        ot.y = pack2(aT[2] * idg, aT[3] * idg);
        ot.z = pack2(aT[4] * idg, aT[5] * idg);
        ot.w = pack2(aT[6] * idg, aT[7] * idg);
        ht4[(size_t)n * 32 + i]      = oh;
        ht4[(size_t)n * 32 + 16 + i] = ot;
    }
}

// ---------- MFMA GEMM: LDS-staged A tile (64 rows), 4 waves x 64-col strips ----------
__global__ __launch_bounds__(256) void k_gemm(
    const unsigned short* __restrict__ ht, const unsigned short* __restrict__ wcat,
    unsigned short* __restrict__ feat, float* __restrict__ res_out, int N) {
    __shared__ __align__(16) unsigned short As[64 * 264];
    int tid = threadIdx.x;
    int row0 = blockIdx.x * 64;
    const uint4* src4 = (const uint4*)ht;
    for (int idx = tid; idx < 64 * 32; idx += 256) {
        int rl = idx >> 5, c16 = idx & 31;
        int gr = row0 + rl; if (gr >= N) gr = N - 1;
        uint4 v = src4[(size_t)gr * 32 + c16];
        *(uint4*)(As + rl * 264 + c16 * 8) = v;
    }
    __syncthreads();
    int wave = tid >> 6, lane = tid & 63;
    int r = lane & 15, q = lane >> 4;
    int colbase = wave * 64;
    const bf16x8* bbase = (const bf16x8*)wcat + (size_t)(colbase + r) * 32;
    const unsigned short* abase = As + r * 264 + q * 8;
    f32x4 acc[4][4] = {};
#pragma unroll
    for (int ks = 0; ks < 8; ks++) {
        bf16x8 a[4], b[4];
#pragma unroll
        for (int rt = 0; rt < 4; rt++)
            a[rt] = *(const bf16x8*)(abase + rt * (16 * 264) + ks * 32);
#pragma unroll
        for (int ct = 0; ct < 4; ct++)
            b[ct] = bbase[(size_t)ct * (16 * 32) + ks * 4 + q];
#pragma unroll
        for (int rt = 0; rt < 4; rt++)
#pragma unroll
            for (int ct = 0; ct < 4; ct++)
                acc[rt][ct] = __builtin_amdgcn_mfma_f32_16x16x32_bf16(a[rt], b[ct], acc[rt][ct], 0, 0, 0);
    }
#pragma unroll
    for (int rt = 0; rt < 4; rt++) {
        int rb = row0 + rt * 16 + q * 4;
#pragma unroll
        for (int ct = 0; ct < 4; ct++) {
            int col = colbase + ct * 16 + r;
#pragma unroll
            for (int reg = 0; reg < 4; reg++) {
                int row = rb + reg;
                if (row >= N) continue;
                float v = acc[rt][ct][reg];
                if (col < 128) feat[(size_t)row * 128 + col] = rne(v);
                else           res_out[(size_t)row * 128 + (col - 128)] = v;
            }
        }
    }
}

// ---------- el/er (prescaled by log2 e for raw v_exp in k_attn) ----------
__global__ void k_el_er(const unsigned* __restrict__ featu,
                        const float* __restrict__ attn_l, const float* __restrict__ attn_r,
                        float* __restrict__ el, float* __restrict__ er, int NH4) {
    int t = blockIdx.x * blockDim.x + threadIdx.x;
    if (t >= NH4) return;
    int n = t >> 2, hd = t & 3;
    const unsigned* f = featu + (size_t)n * 64 + hd * 16;
    const float2* al = (const float2*)(attn_l + hd * 32);
    const float2* ar = (const float2*)(attn_r + hd * 32);
    float sl = 0.f, sr = 0.f;
#pragma unroll
    for (int i = 0; i < 16; i++) {
        unsigned u = f[i];
        float f0 = blo(u), f1 = bhi(u);
        float2 a = al[i], b = ar[i];
        sl = fmaf(f0, a.x, fmaf(f1, a.y, sl));
        sr = fmaf(f0, b.x, fmaf(f1, b.y, sr));
    }
    el[t] = sl * LOG2E;
    er[t] = sr * LOG2E;
}

// ---------- fused attention: wave/node, 16 lanes/edge, 4 groups, unroll-4 ----------
__global__ __launch_bounds__(256) void k_attn(
    const unsigned* __restrict__ est, const int* __restrict__ row_start,
    const float* __restrict__ el, const float* __restrict__ er,
    const unsigned* __restrict__ featu, const float* __restrict__ bias,
    float* __restrict__ out, int N) {
    int n = blockIdx.x * 4 + (threadIdx.x >> 6);
    if (n >= N) return;
    int lane = threadIdx.x & 63;
    int g = lane >> 4, i = lane & 15;
    int hd = i >> 2;
    int rs = row_start[n], re = row_start[n + 1];
    float erh = er[(size_t)n * 4 + hd];
    const uint4* f4 = (const uint4*)featu;
    float acc[8] = {};
    float den = 0.f;
    for (int e = rs + g; e < re; e += 16) {
        int e1 = e + 4, e2 = e + 8, e3 = e + 12;
        bool v1 = e1 < re, v2 = e2 < re, v3 = e3 < re;
        unsigned u0 = est[e];
        unsigned u1 = est[v1 ? e1 : e];
        unsigned u2 = est[v2 ? e2 : e];
        unsigned u3 = est[v3 ? e3 : e];
        attn_edge(u0, true, f4, i, hd, el, erh, acc, den);
        attn_edge(u1, v1, f4, i, hd, el, erh, acc, den);
        attn_edge(u2, v2, f4, i, hd, el, erh, acc, den);
        attn_edge(u3, v3, f4, i, hd, el, erh, acc, den);
    }
#pragma unroll
    for (int off = 16; off <= 32; off <<= 1) {
#pragma unroll
        for (int k = 0; k < 8; k++) acc[k] += __shfl_xor(acc[k], off, 64);
        den += __shfl_xor(den, off, 64);
    }
    if (g == 0) {
        float id = 1.0f / fmaxf(den, 1e-9f);
        float* op = out + (size_t)n * 128 + i * 8;
        const float* bp = bias + i * 8;
        float4 o0 = ((const float4*)op)[0], o1 = ((const float4*)op)[1];
        float4 b0 = ((const float4*)bp)[0], b1 = ((const float4*)bp)[1];
        float4 r0, r1;
        r0.x = fmaf(acc[0], id, o0.x + b0.x);
        r0.y = fmaf(acc[1], id, o0.y + b0.y);
        r0.z = fmaf(acc[2], id, o0.z + b0.z);
        r0.w = fmaf(acc[3], id, o0.w + b0.w);
        r1.x = fmaf(acc[4], id, o1.x + b1.x);
        r1.y = fmaf(acc[5], id, o1.y + b1.y);
        r1.z = fmaf(acc[6], id, o1.z + b1.z);
        r1.w = fmaf(acc[7], id, o1.w + b1.w);
        r0.x = r0.x > 0.f ? r0.x : (__expf(r0.x) - 1.0f);
        r0.y = r0.y > 0.f ? r0.y : (__expf(r0.y) - 1.0f);
        r0.z = r0.z > 0.f ? r0.z : (__expf(r0.z) - 1.0f);
        r0.w = r0.w > 0.f ? r0.w : (__expf(r0.w) - 1.0f);
        r1.x = r1.x > 0.f ? r1.x : (__expf(r1.x) - 1.0f);
        r1.y = r1.y > 0.f ? r1.y : (__expf(r1.y) - 1.0f);
        r1.z = r1.z > 0.f ? r1.z : (__expf(r1.z) - 1.0f);
        r1.w = r1.w > 0.f ? r1.w : (__expf(r1.w) - 1.0f);
        ((float4*)op)[0] = r0;
        ((float4*)op)[1] = r1;
    }
}

extern "C" void kernel_launch(void* const* d_in, const int* in_sizes, int n_in,
                              void* d_out, int out_size, void* d_ws, size_t ws_size,
                              hipStream_t stream) {
    const float* h     = (const float*)d_in[0];
    const float* tt    = (const float*)d_in[1];
    const int*   src   = (const int*)d_in[2];
    const int*   dst   = (const int*)d_in[3];
    const float* w_t   = (const float*)d_in[5];
    const float* b_t   = (const float*)d_in[6];
    const float* W_fc  = (const float*)d_in[7];
    const float* al    = (const float*)d_in[8];
    const float* ar    = (const float*)d_in[9];
    const float* W_res = (const float*)d_in[10];
    const float* bias  = (const float*)d_in[11];

    int N = in_sizes[0] / 128;
    int E = in_sizes[1];
    int B = (N + 1023) / 1024;           // k_scandown assumes B<=64
    int NB = (N + 255) >> BKT_SHIFT;     // buckets; LDS arrays assume NB<=1024

    char* ws = (char*)d_ws;
    size_t off = 0;
    auto alloc = [&](size_t bytes) { void* p = ws + off; off = (off + bytes + 15) & ~(size_t)15; return p; };
    unsigned* htu     = (unsigned*)alloc((size_t)N * 128 * 4);
    unsigned* hbu     = (unsigned*)alloc((size_t)N * 64 * 4);
    unsigned* featu   = (unsigned*)alloc((size_t)N * 64 * 4);   // also aliased as staged
    unsigned* wcat    = (unsigned*)alloc(32768 * 4);
    float2*   w_s     = (float2*)alloc(64 * 8);
    float2*   b_s     = (float2*)alloc(64 * 8);
    float*    el      = (float*)alloc((size_t)N * NH * 4);
    float*    er      = (float*)alloc((size_t)N * NH * 4);
    int*      deg_i   = (int*)alloc((size_t)N * 4);
    int*      row_st  = (int*)alloc((size_t)(N + 1) * 4);
    int*      bkt_cur = (int*)alloc((size_t)NB * 4);
    int*      parts   = (int*)alloc((size_t)B * 4);
    unsigned* est     = (unsigned*)alloc((size_t)E * 4);
    uint2*    staged  = (uint2*)featu;   // consumed by k_binsort before k_gemm writes featu

    hipMemsetAsync(deg_i, 0, (size_t)N * 4, stream);

    int prep_n = N * 64;
    hipLaunchKernelGGL(k_prep, dim3((prep_n + 255) / 256), dim3(256), 0, stream,
                       dst, deg_i, E, h, hbu, prep_n, W_fc, W_res, wcat,
                       w_t, b_t, w_s, b_s);
    hipLaunchKernelGGL(k_blocksum, dim3(B), dim3(1024), 0, stream, deg_i, parts, N);
    hipLaunchKernelGGL(k_scandown, dim3(B), dim3(1024), 0, stream,
                       deg_i, parts, row_st, bkt_cur, N, B);
    hipLaunchKernelGGL(k_binscatter, dim3((E + EPB - 1) / EPB), dim3(256), 0, stream,
                       src, dst, tt, bkt_cur, staged, E, NB);
    hipLaunchKernelGGL(k_binsort, dim3(NB), dim3(256), 0, stream,
                       staged, row_st, est, N);
    hipLaunchKernelGGL(k_agg, dim3((N + 3) / 4), dim3(256), 0, stream,
                       hbu, est, row_st, w_s, b_s, htu, N);
    hipLaunchKernelGGL(k_gemm, dim3((N + 63) / 64), dim3(256), 0, stream,
                       (const unsigned short*)htu, (const unsigned short*)wcat,
                       (unsigned short*)featu, (float*)d_out, N);
    hipLaunchKernelGGL(k_el_er, dim3((N * NH + 255) / 256), dim3(256), 0, stream,
                       featu, al, ar, el, er, N * NH);
    hipLaunchKernelGGL(k_attn, dim3((N + 3) / 4), dim3(256), 0, stream,
                       est, row_st, el, er, featu, bias, (float*)d_out, N);
}